// Round 6
// baseline (143.993 us; speedup 1.0000x reference)
//
#include <hip/hip_runtime.h>
#include <stdint.h>

typedef __attribute__((ext_vector_type(8))) short short8;
typedef __attribute__((ext_vector_type(4))) short short4v;
typedef __attribute__((ext_vector_type(4))) float float4v;
typedef __attribute__((ext_vector_type(16))) float float16v;
typedef __attribute__((ext_vector_type(4))) uint32_t uint4v;

__device__ __forceinline__ short f2bf(float f) {
    union { float f; uint32_t u; } v; v.f = f;
    uint32_t u = v.u;
    uint32_t r = (u + 0x7fffu + ((u >> 16) & 1u)) >> 16;
    return (short)r;
}

// packed 2x fp32 -> 2x bf16 in one dword (low = first arg)
#if __has_builtin(__builtin_amdgcn_cvt_pk_bf16_f32)
typedef __bf16 bf16x2_t __attribute__((ext_vector_type(2)));
__device__ __forceinline__ uint32_t cvt_pk2(float a, float b) {
    union { bf16x2_t v; uint32_t u; } c;
    c.v = __builtin_amdgcn_cvt_pk_bf16_f32(a, b);
    return c.u;
}
#else
__device__ __forceinline__ uint32_t cvt_pk2(float a, float b) {
    union { float f; uint32_t u; } x, y; x.f = a; y.f = b;
    return ((x.u + 0x8000u) >> 16) | ((y.u + 0x8000u) & 0xFFFF0000u);
}
#endif

// ---------------- merged weight transpose-convert ----------------

__global__ __launch_bounds__(256) void cvtW_kernel(const float* __restrict__ wqkv,
                                                   const float* __restrict__ wproj,
                                                   short* __restrict__ outq,
                                                   short* __restrict__ outp) {
    int idx = blockIdx.x * 256 + threadIdx.x;
    if (idx < 196608) {
        int n = idx >> 8, k = idx & 255;
        outq[idx] = f2bf(wqkv[k * 768 + n]);
    } else {
        int i = idx - 196608;
        int n = i >> 8, k = i & 255;
        outp[i] = f2bf(wproj[k * 256 + n]);
    }
}

// ---------------- GEMM: C = A(Mx256) * Bt(Nx256)^T + bias, 128x64 tile -------
// MODE 0: A fp32 (x), bf16-converted during staging; outputs Q/K/V (B,H,N,D),
//         Q pre-scaled by log2(e).  MODE 1: A bf16; fp32 out.

template<int MODE>
__global__ __launch_bounds__(256) void gemm_kernel(
    const void* __restrict__ Ap, const short* __restrict__ Bt,
    const float* __restrict__ bias,
    short* __restrict__ outQ, short* __restrict__ outK, short* __restrict__ outV,
    float* __restrict__ outP)
{
    const int K = 256;
    int m0 = blockIdx.x * 128;
    int n0 = blockIdx.y * 64;
    int tid = threadIdx.x;
    int wave = tid >> 6, lane = tid & 63, quad = lane >> 4, lc = lane & 15;

    __shared__ __align__(16) short As[128 * 48];
    __shared__ __align__(16) short Bs[64 * 48];

    float4v acc[2][4];
    #pragma unroll
    for (int s = 0; s < 2; ++s)
        #pragma unroll
        for (int t = 0; t < 4; ++t) acc[s][t] = (float4v){0.f, 0.f, 0.f, 0.f};

    int srow = tid >> 2, sseg = tid & 3;

    for (int c = 0; c < K; c += 32) {
        __syncthreads();
        #pragma unroll
        for (int s = 0; s < 2; ++s) {
            int row = srow + s * 64;
            if (MODE == 0) {
                const float* src = (const float*)Ap + (size_t)(m0 + row) * K + c + sseg * 8;
                float4 f0 = *(const float4*)src;
                float4 f1 = *(const float4*)(src + 4);
                uint4v u; u.x = cvt_pk2(f0.x, f0.y); u.y = cvt_pk2(f0.z, f0.w);
                u.z = cvt_pk2(f1.x, f1.y); u.w = cvt_pk2(f1.z, f1.w);
                *(uint4v*)(&As[row * 48 + sseg * 8]) = u;
            } else {
                *(short8*)(&As[row * 48 + sseg * 8]) =
                    *(const short8*)((const short*)Ap + (size_t)(m0 + row) * K + c + sseg * 8);
            }
        }
        *(short8*)(&Bs[srow * 48 + sseg * 8]) =
            *(const short8*)(Bt + (size_t)(n0 + srow) * K + c + sseg * 8);
        __syncthreads();

        #pragma unroll
        for (int s = 0; s < 2; ++s) {
            short8 af = *(short8*)(&As[(s * 64 + wave * 16 + lc) * 48 + quad * 8]);
            #pragma unroll
            for (int t = 0; t < 4; ++t) {
                short8 bf = *(short8*)(&Bs[(t * 16 + lc) * 48 + quad * 8]);
                acc[s][t] = __builtin_amdgcn_mfma_f32_16x16x32_bf16(af, bf, acc[s][t], 0, 0, 0);
            }
        }
    }

    #pragma unroll
    for (int s = 0; s < 2; ++s)
    #pragma unroll
    for (int t = 0; t < 4; ++t) {
        int cg = n0 + t * 16 + lc;
        float bv = bias[cg];
        #pragma unroll
        for (int r = 0; r < 4; ++r) {
            int rg = m0 + s * 64 + wave * 16 + quad * 4 + r;
            float val = acc[s][t][r] + bv;
            if (MODE == 0) {
                int sq = cg >> 8, rem = cg & 255, h = rem >> 4, d = rem & 15;
                int b = rg >> 11, n = rg & 2047;
                if (sq == 0) val *= 1.4426950408889634f;  // fold log2(e) into Q
                short* dst = (sq == 0) ? outQ : ((sq == 1) ? outK : outV);
                dst[((((size_t)b * 16 + h) * 2048 + n) << 4) + d] = f2bf(val);
            } else {
                outP[(size_t)rg * 256 + cg] = val;
            }
        }
    }
}

// ---------------- flash attention, 32x32x16 MFMA, no P round-trip ----------------
// grid: (N/128, B*H), 256 threads (4 waves); wave w owns q rows qbase+w*32..+32.
// S^T = K * Q^T  (C-layout col=q). exp2 in-regs; packed C regs ARE the B-operand
// of O^T = [V^T;1;...] * P^T.  Slot->key map forced by the 32x32 C/D layout:
//   key(s) = (s&0x33) | ((s&4)<<1) | ((s&8)>>1)  (swap bits 2<->3), folded into
// Vt staging.  A-operand rows: row m<16 -> V^T dim m; ALL rows m>=16 -> ones row
// (min(m,16)): D rows 17..31 are never read, so they may hold garbage — this
// kills both the divergent select (r4) and the universal zero-row reads (r5).
// Lanes m>=16 read the same LDS address -> broadcast, conflict-free.

__global__ __launch_bounds__(256) void attn_kernel(
    const short* __restrict__ Q, const short* __restrict__ Kp, const short* __restrict__ V,
    short* __restrict__ Out)
{
    const int N = 2048;
    int bh = blockIdx.y;
    int b = bh >> 4, h = bh & 15;
    int tid = threadIdx.x;
    int wave = tid >> 6, lane = tid & 63;
    int m = lane & 31, hi = lane >> 5;
    int qbase = blockIdx.x * 128 + wave * 32;

    const short* Qh = Q + (size_t)bh * N * 16;
    const short* Kh = Kp + (size_t)bh * N * 16;
    const short* Vh = V + (size_t)bh * N * 16;

    // rows 0-15: V^T per 256-key super-chunk; row 16: ones (written once)
    __shared__ __align__(16) short Vt[17][264];

    if (tid < 16) {   // one-time ones-row init
        short8 f8;
        #pragma unroll
        for (int j = 0; j < 8; ++j) f8[j] = (short)0x3F80;
        *(short8*)(&Vt[16][tid * 16]) = f8;
        *(short8*)(&Vt[16][tid * 16 + 8]) = f8;
    }

    short8 qf = *(const short8*)(Qh + (size_t)(qbase + m) * 16 + hi * 8);

    float16v Oacc, zf;
    #pragma unroll
    for (int j = 0; j < 16; ++j) { Oacc[j] = 0.f; zf[j] = 0.f; }

    int rEff = (m < 16) ? m : 16;   // A-operand source row (hoisted)

    int sd = tid & 15, sa = tid >> 4;   // thread stages slots sa*4..sa*4+3, dim sd
    int kb = ((sa & 1) << 3) | (((sa >> 1) & 1) << 2) | ((sa >> 2) << 4);

    for (int sc = 0; sc < N; sc += 256) {
        __syncthreads();
        #pragma unroll
        for (int cc = 0; cc < 4; ++cc) {
            const short* vp = Vh + (size_t)(sc + cc * 64 + kb) * 16 + sd;
            short4v pack;
            pack.x = vp[0]; pack.y = vp[16]; pack.z = vp[32]; pack.w = vp[48];
            *(short4v*)(&Vt[sd][cc * 64 + sa * 4]) = pack;
        }
        __syncthreads();

        #pragma unroll
        for (int it = 0; it < 4; ++it) {
            int c = sc + it * 64;
            short8 kf1 = *(const short8*)(Kh + (size_t)(c + m) * 16 + hi * 8);
            short8 kf2 = *(const short8*)(Kh + (size_t)(c + 32 + m) * 16 + hi * 8);

            float16v S1 = __builtin_amdgcn_mfma_f32_32x32x16_bf16(kf1, qf, zf, 0, 0, 0);
            float16v S2 = __builtin_amdgcn_mfma_f32_32x32x16_bf16(kf2, qf, zf, 0, 0, 0);

            union { uint4v u; short8 s; } pA, pB, pC, pD;
            pA.u = (uint4v){
                cvt_pk2(__builtin_amdgcn_exp2f(S1[0]), __builtin_amdgcn_exp2f(S1[1])),
                cvt_pk2(__builtin_amdgcn_exp2f(S1[2]), __builtin_amdgcn_exp2f(S1[3])),
                cvt_pk2(__builtin_amdgcn_exp2f(S1[4]), __builtin_amdgcn_exp2f(S1[5])),
                cvt_pk2(__builtin_amdgcn_exp2f(S1[6]), __builtin_amdgcn_exp2f(S1[7]))};
            pB.u = (uint4v){
                cvt_pk2(__builtin_amdgcn_exp2f(S1[8]),  __builtin_amdgcn_exp2f(S1[9])),
                cvt_pk2(__builtin_amdgcn_exp2f(S1[10]), __builtin_amdgcn_exp2f(S1[11])),
                cvt_pk2(__builtin_amdgcn_exp2f(S1[12]), __builtin_amdgcn_exp2f(S1[13])),
                cvt_pk2(__builtin_amdgcn_exp2f(S1[14]), __builtin_amdgcn_exp2f(S1[15]))};
            pC.u = (uint4v){
                cvt_pk2(__builtin_amdgcn_exp2f(S2[0]), __builtin_amdgcn_exp2f(S2[1])),
                cvt_pk2(__builtin_amdgcn_exp2f(S2[2]), __builtin_amdgcn_exp2f(S2[3])),
                cvt_pk2(__builtin_amdgcn_exp2f(S2[4]), __builtin_amdgcn_exp2f(S2[5])),
                cvt_pk2(__builtin_amdgcn_exp2f(S2[6]), __builtin_amdgcn_exp2f(S2[7]))};
            pD.u = (uint4v){
                cvt_pk2(__builtin_amdgcn_exp2f(S2[8]),  __builtin_amdgcn_exp2f(S2[9])),
                cvt_pk2(__builtin_amdgcn_exp2f(S2[10]), __builtin_amdgcn_exp2f(S2[11])),
                cvt_pk2(__builtin_amdgcn_exp2f(S2[12]), __builtin_amdgcn_exp2f(S2[13])),
                cvt_pk2(__builtin_amdgcn_exp2f(S2[14]), __builtin_amdgcn_exp2f(S2[15]))};

            #pragma unroll
            for (int p = 0; p < 4; ++p) {
                short8 vf = *(const short8*)(&Vt[rEff][it * 64 + p * 16 + hi * 8]);
                short8 pf = (p == 0) ? pA.s : (p == 1) ? pB.s : (p == 2) ? pC.s : pD.s;
                Oacc = __builtin_amdgcn_mfma_f32_32x32x16_bf16(vf, pf, Oacc, 0, 0, 0);
            }
        }
    }

    // epilogue: L = row 16 (reg 8, hi==0 lanes); O[q][d] = Oacc_d / L
    float Lq = __shfl(Oacc[8], m, 64);
    float inv = 1.0f / Lq;
    uint32_t o0 = cvt_pk2(Oacc[0] * inv, Oacc[1] * inv);
    uint32_t o1 = cvt_pk2(Oacc[2] * inv, Oacc[3] * inv);
    uint32_t o2 = cvt_pk2(Oacc[4] * inv, Oacc[5] * inv);
    uint32_t o3 = cvt_pk2(Oacc[6] * inv, Oacc[7] * inv);
    short* row = Out + ((size_t)(b * 2048 + qbase + m)) * 256 + h * 16;
    uint2 w0; w0.x = o0; w0.y = o1;
    uint2 w1; w1.x = o2; w1.y = o3;
    *(uint2*)(row + hi * 4) = w0;
    *(uint2*)(row + 8 + hi * 4) = w1;
}

// ---------------- launcher ----------------

extern "C" void kernel_launch(void* const* d_in, const int* in_sizes, int n_in,
                              void* d_out, int out_size, void* d_ws, size_t ws_size,
                              hipStream_t stream) {
    const float* x      = (const float*)d_in[0];
    const float* w_qkv  = (const float*)d_in[1];
    const float* b_qkv  = (const float*)d_in[2];
    const float* w_proj = (const float*)d_in[3];
    const float* b_proj = (const float*)d_in[4];
    float* out = (float*)d_out;

    short* wqkvT  = (short*)d_ws;          // 768*256
    short* wprojT = wqkvT + 196608;        // 256*256
    short* Qb     = wprojT + 65536;        // 4*16*2048*16
    short* Kb     = Qb + 2097152;
    short* Vb     = Kb + 2097152;
    short* Ab     = Vb + 2097152;          // 8192*256 attention output

    cvtW_kernel<<<1024, 256, 0, stream>>>(w_qkv, w_proj, wqkvT, wprojT);

    gemm_kernel<0><<<dim3(64, 12), 256, 0, stream>>>(x, wqkvT, b_qkv, Qb, Kb, Vb, nullptr);

    attn_kernel<<<dim3(16, 64), 256, 0, stream>>>(Qb, Kb, Vb, Ab);

    gemm_kernel<1><<<dim3(64, 4), 256, 0, stream>>>(Ab, wprojT, b_proj,
                                                    nullptr, nullptr, nullptr, out);
}

// Round 7
// 143.470 us; speedup vs baseline: 1.0036x; 1.0036x over previous
//
#include <hip/hip_runtime.h>
#include <stdint.h>

typedef __attribute__((ext_vector_type(8))) short short8;
typedef __attribute__((ext_vector_type(4))) short short4v;
typedef __attribute__((ext_vector_type(4))) float float4v;
typedef __attribute__((ext_vector_type(16))) float float16v;
typedef __attribute__((ext_vector_type(4))) uint32_t uint4v;

__device__ __forceinline__ short f2bf(float f) {
    union { float f; uint32_t u; } v; v.f = f;
    uint32_t u = v.u;
    uint32_t r = (u + 0x7fffu + ((u >> 16) & 1u)) >> 16;
    return (short)r;
}

// packed 2x fp32 -> 2x bf16 in one dword (low = first arg)
#if __has_builtin(__builtin_amdgcn_cvt_pk_bf16_f32)
typedef __bf16 bf16x2_t __attribute__((ext_vector_type(2)));
__device__ __forceinline__ uint32_t cvt_pk2(float a, float b) {
    union { bf16x2_t v; uint32_t u; } c;
    c.v = __builtin_amdgcn_cvt_pk_bf16_f32(a, b);
    return c.u;
}
#else
__device__ __forceinline__ uint32_t cvt_pk2(float a, float b) {
    union { float f; uint32_t u; } x, y; x.f = a; y.f = b;
    return ((x.u + 0x8000u) >> 16) | ((y.u + 0x8000u) & 0xFFFF0000u);
}
#endif

// ---------------- merged weight transpose-convert ----------------

__global__ __launch_bounds__(256) void cvtW_kernel(const float* __restrict__ wqkv,
                                                   const float* __restrict__ wproj,
                                                   short* __restrict__ outq,
                                                   short* __restrict__ outp) {
    int idx = blockIdx.x * 256 + threadIdx.x;
    if (idx < 196608) {
        int n = idx >> 8, k = idx & 255;
        outq[idx] = f2bf(wqkv[k * 768 + n]);
    } else {
        int i = idx - 196608;
        int n = i >> 8, k = i & 255;
        outp[i] = f2bf(wproj[k * 256 + n]);
    }
}

// ---------------- GEMM: C = A(Mx256) * Bt(Nx256)^T + bias ----------------
// A-stationary: each block owns a 64-row A-tile held ENTIRELY in registers
// (per-lane MFMA A-fragments, loaded once) and loops over NT n-tiles,
// staging only B in LDS (with register prefetch of the next tile).
// This kills the A re-fetch (was N/64 passes over x = 384 MB for QKV).
// MODE 0: A fp32 (x), cvt during load; out Q/K/V (B,H,N,D), Q scaled log2(e).
// MODE 1: A bf16; out fp32.
// grid: 256 blocks = 128 m-tiles x 2 n-splits.

template<int MODE>
__global__ __launch_bounds__(256) void gemm_kernel(
    const void* __restrict__ Ap, const short* __restrict__ Bt,
    const float* __restrict__ bias,
    short* __restrict__ outQ, short* __restrict__ outK, short* __restrict__ outV,
    float* __restrict__ outP)
{
    const int K = 256;
    const int NT = (MODE == 0) ? 6 : 2;          // n-tiles per block
    const int NSBASE = (MODE == 0) ? 384 : 128;  // n-split offset
    int bx = blockIdx.x;
    int m0 = (bx >> 1) * 64;
    int ns = bx & 1;
    int tid = threadIdx.x;
    int wave = tid >> 6, lane = tid & 63, quad = lane >> 4, lc = lane & 15;

    __shared__ __align__(16) short Bs[64 * 264];

    // ---- A fragments: areg[ko] = A[m0+wave*16+lc][ko*32+quad*8 ..+8] ----
    short8 areg[8];
    if (MODE == 0) {
        const float* arow = (const float*)Ap + (size_t)(m0 + wave * 16 + lc) * K;
        #pragma unroll
        for (int ko = 0; ko < 8; ++ko) {
            float4 f0 = *(const float4*)(arow + ko * 32 + quad * 8);
            float4 f1 = *(const float4*)(arow + ko * 32 + quad * 8 + 4);
            union { uint4v u; short8 s; } c;
            c.u = (uint4v){cvt_pk2(f0.x, f0.y), cvt_pk2(f0.z, f0.w),
                           cvt_pk2(f1.x, f1.y), cvt_pk2(f1.z, f1.w)};
            areg[ko] = c.s;
        }
    } else {
        const short* arow = (const short*)Ap + (size_t)(m0 + wave * 16 + lc) * K;
        #pragma unroll
        for (int ko = 0; ko < 8; ++ko)
            areg[ko] = *(const short8*)(arow + ko * 32 + quad * 8);
    }

    // ---- B prefetch (j = 0) ----
    int srow = tid >> 2, sseg = tid & 3;  // each thread stages 64 shorts of one row
    short8 breg[8];
    {
        const short* bsrc = Bt + (size_t)(ns * NSBASE + srow) * K + sseg * 64;
        #pragma unroll
        for (int k = 0; k < 8; ++k) breg[k] = *(const short8*)(bsrc + k * 8);
    }

    for (int j = 0; j < NT; ++j) {
        __syncthreads();   // all waves done reading Bs from previous tile
        {
            short* bdst = &Bs[srow * 264 + sseg * 64];
            #pragma unroll
            for (int k = 0; k < 8; ++k) *(short8*)(bdst + k * 8) = breg[k];
        }
        if (j + 1 < NT) {   // prefetch next tile; completes during compute
            const short* bn = Bt + (size_t)(ns * NSBASE + (j + 1) * 64 + srow) * K + sseg * 64;
            #pragma unroll
            for (int k = 0; k < 8; ++k) breg[k] = *(const short8*)(bn + k * 8);
        }
        __syncthreads();   // Bs ready

        int n0 = ns * NSBASE + j * 64;
        float4v acc[4];
        #pragma unroll
        for (int t = 0; t < 4; ++t) acc[t] = (float4v){0.f, 0.f, 0.f, 0.f};

        #pragma unroll
        for (int ko = 0; ko < 8; ++ko) {
            #pragma unroll
            for (int t = 0; t < 4; ++t) {
                short8 bf = *(short8*)(&Bs[(t * 16 + lc) * 264 + ko * 32 + quad * 8]);
                acc[t] = __builtin_amdgcn_mfma_f32_16x16x32_bf16(areg[ko], bf, acc[t], 0, 0, 0);
            }
        }

        #pragma unroll
        for (int t = 0; t < 4; ++t) {
            int cg = n0 + t * 16 + lc;
            float bv = bias[cg];
            #pragma unroll
            for (int r = 0; r < 4; ++r) {
                int rg = m0 + wave * 16 + quad * 4 + r;
                float val = acc[t][r] + bv;
                if (MODE == 0) {
                    int sq = cg >> 8, rem = cg & 255, h = rem >> 4, d = rem & 15;
                    int b = rg >> 11, n = rg & 2047;
                    if (sq == 0) val *= 1.4426950408889634f;  // fold log2(e) into Q
                    short* dst = (sq == 0) ? outQ : ((sq == 1) ? outK : outV);
                    dst[((((size_t)b * 16 + h) * 2048 + n) << 4) + d] = f2bf(val);
                } else {
                    outP[(size_t)rg * 256 + cg] = val;
                }
            }
        }
    }
}

// ---------------- flash attention (r4 structure — fastest measured) ----------------
// grid: (N/128, B*H), 256 threads (4 waves); wave w owns q rows qbase+w*32..+32.
// S^T = K * Q^T  (C-layout col=q). exp2 in-regs; packed C regs ARE the B-operand
// of O^T = [V^T;1;0] * P^T.  Slot->key map forced by the 32x32 C/D layout:
//   key(s) = (s&0x33) | ((s&4)<<1) | ((s&8)>>1)  (swap bits 2<->3), folded into
// Vt staging.  A-operand rows 16+ come from REGISTERS via a predicated select
// (ones row m==16 for L, zeros above) — measured faster than any LDS-row
// variant (59.0 vs 62.6/64.3 µs in r5/r6).

__global__ __launch_bounds__(256) void attn_kernel(
    const short* __restrict__ Q, const short* __restrict__ Kp, const short* __restrict__ V,
    short* __restrict__ Out)
{
    const int N = 2048;
    int bh = blockIdx.y;
    int b = bh >> 4, h = bh & 15;
    int tid = threadIdx.x;
    int wave = tid >> 6, lane = tid & 63;
    int m = lane & 31, hi = lane >> 5;
    int qbase = blockIdx.x * 128 + wave * 32;

    const short* Qh = Q + (size_t)bh * N * 16;
    const short* Kh = Kp + (size_t)bh * N * 16;
    const short* Vh = V + (size_t)bh * N * 16;

    // Vt[d][slot]: 256-key super-chunk; slot s -> key (s>>6)*64 + swap23(s&63)
    __shared__ __align__(16) short Vt[16][264];

    short8 qf = *(const short8*)(Qh + (size_t)(qbase + m) * 16 + hi * 8);

    short8 ones, zeros;
    #pragma unroll
    for (int j = 0; j < 8; ++j) { ones[j] = (short)0x3F80; zeros[j] = 0; }

    float16v Oacc, zf;
    #pragma unroll
    for (int j = 0; j < 16; ++j) { Oacc[j] = 0.f; zf[j] = 0.f; }

    int sd = tid & 15, sa = tid >> 4;   // thread stages slots sa*4..sa*4+3, dim sd
    int kb = ((sa & 1) << 3) | (((sa >> 1) & 1) << 2) | ((sa >> 2) << 4);

    for (int sc = 0; sc < N; sc += 256) {
        __syncthreads();
        #pragma unroll
        for (int cc = 0; cc < 4; ++cc) {
            const short* vp = Vh + (size_t)(sc + cc * 64 + kb) * 16 + sd;
            short4v pack;
            pack.x = vp[0]; pack.y = vp[16]; pack.z = vp[32]; pack.w = vp[48];
            *(short4v*)(&Vt[sd][cc * 64 + sa * 4]) = pack;
        }
        __syncthreads();

        #pragma unroll
        for (int it = 0; it < 4; ++it) {
            int c = sc + it * 64;
            short8 kf1 = *(const short8*)(Kh + (size_t)(c + m) * 16 + hi * 8);
            short8 kf2 = *(const short8*)(Kh + (size_t)(c + 32 + m) * 16 + hi * 8);

            float16v S1 = __builtin_amdgcn_mfma_f32_32x32x16_bf16(kf1, qf, zf, 0, 0, 0);
            float16v S2 = __builtin_amdgcn_mfma_f32_32x32x16_bf16(kf2, qf, zf, 0, 0, 0);

            union { uint4v u; short8 s; } pA, pB, pC, pD;
            pA.u = (uint4v){
                cvt_pk2(__builtin_amdgcn_exp2f(S1[0]), __builtin_amdgcn_exp2f(S1[1])),
                cvt_pk2(__builtin_amdgcn_exp2f(S1[2]), __builtin_amdgcn_exp2f(S1[3])),
                cvt_pk2(__builtin_amdgcn_exp2f(S1[4]), __builtin_amdgcn_exp2f(S1[5])),
                cvt_pk2(__builtin_amdgcn_exp2f(S1[6]), __builtin_amdgcn_exp2f(S1[7]))};
            pB.u = (uint4v){
                cvt_pk2(__builtin_amdgcn_exp2f(S1[8]),  __builtin_amdgcn_exp2f(S1[9])),
                cvt_pk2(__builtin_amdgcn_exp2f(S1[10]), __builtin_amdgcn_exp2f(S1[11])),
                cvt_pk2(__builtin_amdgcn_exp2f(S1[12]), __builtin_amdgcn_exp2f(S1[13])),
                cvt_pk2(__builtin_amdgcn_exp2f(S1[14]), __builtin_amdgcn_exp2f(S1[15]))};
            pC.u = (uint4v){
                cvt_pk2(__builtin_amdgcn_exp2f(S2[0]), __builtin_amdgcn_exp2f(S2[1])),
                cvt_pk2(__builtin_amdgcn_exp2f(S2[2]), __builtin_amdgcn_exp2f(S2[3])),
                cvt_pk2(__builtin_amdgcn_exp2f(S2[4]), __builtin_amdgcn_exp2f(S2[5])),
                cvt_pk2(__builtin_amdgcn_exp2f(S2[6]), __builtin_amdgcn_exp2f(S2[7]))};
            pD.u = (uint4v){
                cvt_pk2(__builtin_amdgcn_exp2f(S2[8]),  __builtin_amdgcn_exp2f(S2[9])),
                cvt_pk2(__builtin_amdgcn_exp2f(S2[10]), __builtin_amdgcn_exp2f(S2[11])),
                cvt_pk2(__builtin_amdgcn_exp2f(S2[12]), __builtin_amdgcn_exp2f(S2[13])),
                cvt_pk2(__builtin_amdgcn_exp2f(S2[14]), __builtin_amdgcn_exp2f(S2[15]))};

            #pragma unroll
            for (int p = 0; p < 4; ++p) {
                short8 vf;
                if (m < 16)      vf = *(const short8*)(&Vt[m][it * 64 + p * 16 + hi * 8]);
                else if (m == 16) vf = ones;
                else              vf = zeros;
                short8 pf = (p == 0) ? pA.s : (p == 1) ? pB.s : (p == 2) ? pC.s : pD.s;
                Oacc = __builtin_amdgcn_mfma_f32_32x32x16_bf16(vf, pf, Oacc, 0, 0, 0);
            }
        }
    }

    // epilogue: L = row 16 (reg 8, hi==0 lanes); O[q][d] = Oacc_d / L
    float Lq = __shfl(Oacc[8], m, 64);
    float inv = 1.0f / Lq;
    uint32_t o0 = cvt_pk2(Oacc[0] * inv, Oacc[1] * inv);
    uint32_t o1 = cvt_pk2(Oacc[2] * inv, Oacc[3] * inv);
    uint32_t o2 = cvt_pk2(Oacc[4] * inv, Oacc[5] * inv);
    uint32_t o3 = cvt_pk2(Oacc[6] * inv, Oacc[7] * inv);
    short* row = Out + ((size_t)(b * 2048 + qbase + m)) * 256 + h * 16;
    uint2 w0; w0.x = o0; w0.y = o1;
    uint2 w1; w1.x = o2; w1.y = o3;
    *(uint2*)(row + hi * 4) = w0;
    *(uint2*)(row + 8 + hi * 4) = w1;
}

// ---------------- launcher ----------------

extern "C" void kernel_launch(void* const* d_in, const int* in_sizes, int n_in,
                              void* d_out, int out_size, void* d_ws, size_t ws_size,
                              hipStream_t stream) {
    const float* x      = (const float*)d_in[0];
    const float* w_qkv  = (const float*)d_in[1];
    const float* b_qkv  = (const float*)d_in[2];
    const float* w_proj = (const float*)d_in[3];
    const float* b_proj = (const float*)d_in[4];
    float* out = (float*)d_out;

    short* wqkvT  = (short*)d_ws;          // 768*256
    short* wprojT = wqkvT + 196608;        // 256*256
    short* Qb     = wprojT + 65536;        // 4*16*2048*16
    short* Kb     = Qb + 2097152;
    short* Vb     = Kb + 2097152;
    short* Ab     = Vb + 2097152;          // 8192*256 attention output

    cvtW_kernel<<<1024, 256, 0, stream>>>(w_qkv, w_proj, wqkvT, wprojT);

    gemm_kernel<0><<<256, 256, 0, stream>>>(x, wqkvT, b_qkv, Qb, Kb, Vb, nullptr);

    attn_kernel<<<dim3(16, 64), 256, 0, stream>>>(Qb, Kb, Vb, Ab);

    gemm_kernel<1><<<256, 256, 0, stream>>>(Ab, wprojT, b_proj,
                                            nullptr, nullptr, nullptr, out);
}

// Round 8
// 140.914 us; speedup vs baseline: 1.0219x; 1.0181x over previous
//
#include <hip/hip_runtime.h>
#include <stdint.h>

typedef __attribute__((ext_vector_type(8))) short short8;
typedef __attribute__((ext_vector_type(4))) short short4v;
typedef __attribute__((ext_vector_type(4))) float float4v;
typedef __attribute__((ext_vector_type(16))) float float16v;
typedef __attribute__((ext_vector_type(4))) uint32_t uint4v;

__device__ __forceinline__ short f2bf(float f) {
    union { float f; uint32_t u; } v; v.f = f;
    uint32_t u = v.u;
    uint32_t r = (u + 0x7fffu + ((u >> 16) & 1u)) >> 16;
    return (short)r;
}

// packed 2x fp32 -> 2x bf16 in one dword (low = first arg)
#if __has_builtin(__builtin_amdgcn_cvt_pk_bf16_f32)
typedef __bf16 bf16x2_t __attribute__((ext_vector_type(2)));
__device__ __forceinline__ uint32_t cvt_pk2(float a, float b) {
    union { bf16x2_t v; uint32_t u; } c;
    c.v = __builtin_amdgcn_cvt_pk_bf16_f32(a, b);
    return c.u;
}
#else
__device__ __forceinline__ uint32_t cvt_pk2(float a, float b) {
    union { float f; uint32_t u; } x, y; x.f = a; y.f = b;
    return ((x.u + 0x8000u) >> 16) | ((y.u + 0x8000u) & 0xFFFF0000u);
}
#endif

// ---------------- merged weight transpose-convert ----------------

__global__ __launch_bounds__(256) void cvtW_kernel(const float* __restrict__ wqkv,
                                                   const float* __restrict__ wproj,
                                                   short* __restrict__ outq,
                                                   short* __restrict__ outp) {
    int idx = blockIdx.x * 256 + threadIdx.x;
    if (idx < 196608) {
        int n = idx >> 8, k = idx & 255;
        outq[idx] = f2bf(wqkv[k * 768 + n]);
    } else {
        int i = idx - 196608;
        int n = i >> 8, k = i & 255;
        outp[i] = f2bf(wproj[k * 256 + n]);
    }
}

// ---------------- GEMM (r5 version — best measured): 64x64 tile ----------------
// MODE 0: A fp32 (x), bf16-converted during LDS staging; outputs Q/K/V
//         (B,H,N,D), Q pre-scaled by log2(e).  MODE 1: A bf16; fp32 out.

template<int MODE>
__global__ __launch_bounds__(256) void gemm_kernel(
    const void* __restrict__ Ap, const short* __restrict__ Bt,
    const float* __restrict__ bias,
    short* __restrict__ outQ, short* __restrict__ outK, short* __restrict__ outV,
    float* __restrict__ outP)
{
    const int K = 256;
    int m0 = blockIdx.x * 64;
    int n0 = blockIdx.y * 64;
    int tid = threadIdx.x;
    int wave = tid >> 6, lane = tid & 63, quad = lane >> 4, lc = lane & 15;

    __shared__ __align__(16) short As[64 * 48];
    __shared__ __align__(16) short Bs[64 * 48];

    float4v acc[4];
    #pragma unroll
    for (int t = 0; t < 4; ++t) acc[t] = (float4v){0.f, 0.f, 0.f, 0.f};

    int srow = tid >> 2, sseg = tid & 3;

    for (int c = 0; c < K; c += 32) {
        __syncthreads();
        if (MODE == 0) {
            const float* src = (const float*)Ap + (size_t)(m0 + srow) * K + c + sseg * 8;
            float4 f0 = *(const float4*)src;
            float4 f1 = *(const float4*)(src + 4);
            uint4v u; u.x = cvt_pk2(f0.x, f0.y); u.y = cvt_pk2(f0.z, f0.w);
            u.z = cvt_pk2(f1.x, f1.y); u.w = cvt_pk2(f1.z, f1.w);
            *(uint4v*)(&As[srow * 48 + sseg * 8]) = u;
        } else {
            *(short8*)(&As[srow * 48 + sseg * 8]) =
                *(const short8*)((const short*)Ap + (size_t)(m0 + srow) * K + c + sseg * 8);
        }
        *(short8*)(&Bs[srow * 48 + sseg * 8]) =
            *(const short8*)(Bt + (size_t)(n0 + srow) * K + c + sseg * 8);
        __syncthreads();

        short8 af = *(short8*)(&As[(wave * 16 + lc) * 48 + quad * 8]);
        #pragma unroll
        for (int t = 0; t < 4; ++t) {
            short8 bf = *(short8*)(&Bs[(t * 16 + lc) * 48 + quad * 8]);
            acc[t] = __builtin_amdgcn_mfma_f32_16x16x32_bf16(af, bf, acc[t], 0, 0, 0);
        }
    }

    #pragma unroll
    for (int t = 0; t < 4; ++t) {
        int cg = n0 + t * 16 + lc;
        float bv = bias[cg];
        #pragma unroll
        for (int r = 0; r < 4; ++r) {
            int rg = m0 + wave * 16 + quad * 4 + r;
            float val = acc[t][r] + bv;
            if (MODE == 0) {
                int sq = cg >> 8, rem = cg & 255, h = rem >> 4, d = rem & 15;
                int b = rg >> 11, n = rg & 2047;
                if (sq == 0) val *= 1.4426950408889634f;  // fold log2(e) into Q
                short* dst = (sq == 0) ? outQ : ((sq == 1) ? outK : outV);
                dst[((((size_t)b * 16 + h) * 2048 + n) << 4) + d] = f2bf(val);
            } else {
                outP[(size_t)rg * 256 + cg] = val;
            }
        }
    }
}

// ---------------- flash attention (r4 structure) with optional split-K -------
// grid: (N/128, B*H, SPLIT); wave w owns q rows qbase+w*32..+32, keys
// [z*N/SPLIT, (z+1)*N/SPLIT).  S^T = K*Q^T; exp2 in-regs; packed C regs are
// the B-operand of O^T = [V^T;1;0]*P^T (slot->key bit-swap folded into Vt).
// SPLIT=1: normalize and write bf16 Out.  SPLIT=2: write fp32 partial rows
// 0..15 (O^T) + row 16 (L) to Pws; combine kernel finishes.

template<int SPLIT>
__global__ __launch_bounds__(256) void attn_kernel(
    const short* __restrict__ Q, const short* __restrict__ Kp, const short* __restrict__ V,
    short* __restrict__ Out, float* __restrict__ Pws)
{
    const int N = 2048;
    const int KEYS = N / SPLIT;
    int bh = blockIdx.y;
    int half = (SPLIT == 2) ? blockIdx.z : 0;
    int b = bh >> 4, h = bh & 15;
    int tid = threadIdx.x;
    int wave = tid >> 6, lane = tid & 63;
    int m = lane & 31, hi = lane >> 5;
    int qbase = blockIdx.x * 128 + wave * 32;

    const short* Qh = Q + (size_t)bh * N * 16;
    const short* Kh = Kp + (size_t)bh * N * 16;
    const short* Vh = V + (size_t)bh * N * 16;

    __shared__ __align__(16) short Vt[16][264];

    short8 qf = *(const short8*)(Qh + (size_t)(qbase + m) * 16 + hi * 8);

    short8 ones, zeros;
    #pragma unroll
    for (int j = 0; j < 8; ++j) { ones[j] = (short)0x3F80; zeros[j] = 0; }

    float16v Oacc, zf;
    #pragma unroll
    for (int j = 0; j < 16; ++j) { Oacc[j] = 0.f; zf[j] = 0.f; }

    int sd = tid & 15, sa = tid >> 4;
    int kb = ((sa & 1) << 3) | (((sa >> 1) & 1) << 2) | ((sa >> 2) << 4);

    for (int sc = half * KEYS; sc < (half + 1) * KEYS; sc += 256) {
        __syncthreads();
        #pragma unroll
        for (int cc = 0; cc < 4; ++cc) {
            const short* vp = Vh + (size_t)(sc + cc * 64 + kb) * 16 + sd;
            short4v pack;
            pack.x = vp[0]; pack.y = vp[16]; pack.z = vp[32]; pack.w = vp[48];
            *(short4v*)(&Vt[sd][cc * 64 + sa * 4]) = pack;
        }
        __syncthreads();

        #pragma unroll
        for (int it = 0; it < 4; ++it) {
            int c = sc + it * 64;
            short8 kf1 = *(const short8*)(Kh + (size_t)(c + m) * 16 + hi * 8);
            short8 kf2 = *(const short8*)(Kh + (size_t)(c + 32 + m) * 16 + hi * 8);

            float16v S1 = __builtin_amdgcn_mfma_f32_32x32x16_bf16(kf1, qf, zf, 0, 0, 0);
            float16v S2 = __builtin_amdgcn_mfma_f32_32x32x16_bf16(kf2, qf, zf, 0, 0, 0);

            union { uint4v u; short8 s; } pA, pB, pC, pD;
            pA.u = (uint4v){
                cvt_pk2(__builtin_amdgcn_exp2f(S1[0]), __builtin_amdgcn_exp2f(S1[1])),
                cvt_pk2(__builtin_amdgcn_exp2f(S1[2]), __builtin_amdgcn_exp2f(S1[3])),
                cvt_pk2(__builtin_amdgcn_exp2f(S1[4]), __builtin_amdgcn_exp2f(S1[5])),
                cvt_pk2(__builtin_amdgcn_exp2f(S1[6]), __builtin_amdgcn_exp2f(S1[7]))};
            pB.u = (uint4v){
                cvt_pk2(__builtin_amdgcn_exp2f(S1[8]),  __builtin_amdgcn_exp2f(S1[9])),
                cvt_pk2(__builtin_amdgcn_exp2f(S1[10]), __builtin_amdgcn_exp2f(S1[11])),
                cvt_pk2(__builtin_amdgcn_exp2f(S1[12]), __builtin_amdgcn_exp2f(S1[13])),
                cvt_pk2(__builtin_amdgcn_exp2f(S1[14]), __builtin_amdgcn_exp2f(S1[15]))};
            pC.u = (uint4v){
                cvt_pk2(__builtin_amdgcn_exp2f(S2[0]), __builtin_amdgcn_exp2f(S2[1])),
                cvt_pk2(__builtin_amdgcn_exp2f(S2[2]), __builtin_amdgcn_exp2f(S2[3])),
                cvt_pk2(__builtin_amdgcn_exp2f(S2[4]), __builtin_amdgcn_exp2f(S2[5])),
                cvt_pk2(__builtin_amdgcn_exp2f(S2[6]), __builtin_amdgcn_exp2f(S2[7]))};
            pD.u = (uint4v){
                cvt_pk2(__builtin_amdgcn_exp2f(S2[8]),  __builtin_amdgcn_exp2f(S2[9])),
                cvt_pk2(__builtin_amdgcn_exp2f(S2[10]), __builtin_amdgcn_exp2f(S2[11])),
                cvt_pk2(__builtin_amdgcn_exp2f(S2[12]), __builtin_amdgcn_exp2f(S2[13])),
                cvt_pk2(__builtin_amdgcn_exp2f(S2[14]), __builtin_amdgcn_exp2f(S2[15]))};

            #pragma unroll
            for (int p = 0; p < 4; ++p) {
                short8 vf;
                if (m < 16)      vf = *(const short8*)(&Vt[m][it * 64 + p * 16 + hi * 8]);
                else if (m == 16) vf = ones;
                else              vf = zeros;
                short8 pf = (p == 0) ? pA.s : (p == 1) ? pB.s : (p == 2) ? pC.s : pD.s;
                Oacc = __builtin_amdgcn_mfma_f32_32x32x16_bf16(vf, pf, Oacc, 0, 0, 0);
            }
        }
    }

    if (SPLIT == 1) {
        // L = row 16 (reg 8, hi==0 lanes); O[q][d] = Oacc_d / L
        float Lq = __shfl(Oacc[8], m, 64);
        float inv = 1.0f / Lq;
        uint32_t o0 = cvt_pk2(Oacc[0] * inv, Oacc[1] * inv);
        uint32_t o1 = cvt_pk2(Oacc[2] * inv, Oacc[3] * inv);
        uint32_t o2 = cvt_pk2(Oacc[4] * inv, Oacc[5] * inv);
        uint32_t o3 = cvt_pk2(Oacc[6] * inv, Oacc[7] * inv);
        short* row = Out + ((size_t)(b * 2048 + qbase + m)) * 256 + h * 16;
        uint2 w0; w0.x = o0; w0.y = o1;
        uint2 w1; w1.x = o2; w1.y = o3;
        *(uint2*)(row + hi * 4) = w0;
        *(uint2*)(row + 8 + hi * 4) = w1;
    } else {
        // fp32 partials: drow(r,hi) = (r&3) + 8*(r>>2) + 4*hi  (rows 0..15 = V
        // dims, row 16 = L from reg 8 hi==0)
        float* base = Pws + (((size_t)half * 64 + bh) * 16 + blockIdx.x) * (17 * 128);
        int ql = wave * 32 + m;
        #pragma unroll
        for (int r = 0; r < 8; ++r) {
            int drow = (r & 3) + 8 * (r >> 2) + 4 * hi;
            base[drow * 128 + ql] = Oacc[r];
        }
        if (hi == 0) base[16 * 128 + ql] = Oacc[8];
    }
}

// ---------------- split-K combine: O = (O1+O2)/(L1+L2), write bf16 ----------

__global__ __launch_bounds__(256) void attn_combine(const float* __restrict__ Pws,
                                                    short* __restrict__ Out) {
    int qt = blockIdx.x, bh = blockIdx.y;
    int b = bh >> 4, h = bh & 15;
    const float* P1 = Pws + (((size_t)bh) * 16 + qt) * (17 * 128);
    const float* P2 = P1 + (size_t)64 * 16 * 17 * 128;
    int ql = threadIdx.x & 127, dh = threadIdx.x >> 7;
    float L = P1[16 * 128 + ql] + P2[16 * 128 + ql];
    float inv = 1.0f / L;
    float v[8];
    #pragma unroll
    for (int j = 0; j < 8; ++j) {
        int d = dh * 8 + j;
        v[j] = (P1[d * 128 + ql] + P2[d * 128 + ql]) * inv;
    }
    union { uint4v u; short8 s; } c;
    c.u = (uint4v){cvt_pk2(v[0], v[1]), cvt_pk2(v[2], v[3]),
                   cvt_pk2(v[4], v[5]), cvt_pk2(v[6], v[7])};
    int n = qt * 128 + ql;
    *(short8*)(Out + ((size_t)(b * 2048 + n)) * 256 + h * 16 + dh * 8) = c.s;
}

// ---------------- launcher ----------------

extern "C" void kernel_launch(void* const* d_in, const int* in_sizes, int n_in,
                              void* d_out, int out_size, void* d_ws, size_t ws_size,
                              hipStream_t stream) {
    const float* x      = (const float*)d_in[0];
    const float* w_qkv  = (const float*)d_in[1];
    const float* b_qkv  = (const float*)d_in[2];
    const float* w_proj = (const float*)d_in[3];
    const float* b_proj = (const float*)d_in[4];
    float* out = (float*)d_out;

    short* wqkvT  = (short*)d_ws;          // 768*256
    short* wprojT = wqkvT + 196608;        // 256*256
    short* Qb     = wprojT + 65536;        // 4*16*2048*16
    short* Kb     = Qb + 2097152;
    short* Vb     = Kb + 2097152;
    short* Ab     = Vb + 2097152;          // 8192*256 attention output
    float* Pws    = (float*)(Ab + 2097152);
    size_t needed = (size_t)(Ab + 2097152 - (short*)d_ws) * 2
                  + (size_t)2 * 64 * 16 * 17 * 128 * 4;
    bool split = ws_size >= needed;

    cvtW_kernel<<<1024, 256, 0, stream>>>(w_qkv, w_proj, wqkvT, wprojT);

    gemm_kernel<0><<<dim3(128, 12), 256, 0, stream>>>(x, wqkvT, b_qkv, Qb, Kb, Vb, nullptr);

    if (split) {
        attn_kernel<2><<<dim3(16, 64, 2), 256, 0, stream>>>(Qb, Kb, Vb, Ab, Pws);
        attn_combine<<<dim3(16, 64), 256, 0, stream>>>(Pws, Ab);
    } else {
        attn_kernel<1><<<dim3(16, 64), 256, 0, stream>>>(Qb, Kb, Vb, Ab, nullptr);
    }

    gemm_kernel<1><<<dim3(128, 4), 256, 0, stream>>>(Ab, wprojT, b_proj,
                                                     nullptr, nullptr, nullptr, out);
}

// Round 9
// 134.651 us; speedup vs baseline: 1.0694x; 1.0465x over previous
//
#include <hip/hip_runtime.h>
#include <stdint.h>

typedef __attribute__((ext_vector_type(8))) short short8;
typedef __attribute__((ext_vector_type(4))) short short4v;
typedef __attribute__((ext_vector_type(4))) float float4v;
typedef __attribute__((ext_vector_type(16))) float float16v;
typedef __attribute__((ext_vector_type(4))) uint32_t uint4v;

__device__ __forceinline__ short f2bf(float f) {
    union { float f; uint32_t u; } v; v.f = f;
    uint32_t u = v.u;
    uint32_t r = (u + 0x7fffu + ((u >> 16) & 1u)) >> 16;
    return (short)r;
}

// packed 2x fp32 -> 2x bf16 in one dword (low = first arg)
#if __has_builtin(__builtin_amdgcn_cvt_pk_bf16_f32)
typedef __bf16 bf16x2_t __attribute__((ext_vector_type(2)));
__device__ __forceinline__ uint32_t cvt_pk2(float a, float b) {
    union { bf16x2_t v; uint32_t u; } c;
    c.v = __builtin_amdgcn_cvt_pk_bf16_f32(a, b);
    return c.u;
}
#else
__device__ __forceinline__ uint32_t cvt_pk2(float a, float b) {
    union { float f; uint32_t u; } x, y; x.f = a; y.f = b;
    return ((x.u + 0x8000u) >> 16) | ((y.u + 0x8000u) & 0xFFFF0000u);
}
#endif

// ---------------- merged weight transpose-convert ----------------

__global__ __launch_bounds__(256) void cvtW_kernel(const float* __restrict__ wqkv,
                                                   const float* __restrict__ wproj,
                                                   short* __restrict__ outq,
                                                   short* __restrict__ outp) {
    int idx = blockIdx.x * 256 + threadIdx.x;
    if (idx < 196608) {
        int n = idx >> 8, k = idx & 255;
        outq[idx] = f2bf(wqkv[k * 768 + n]);
    } else {
        int i = idx - 196608;
        int n = i >> 8, k = i & 255;
        outp[i] = f2bf(wproj[k * 256 + n]);
    }
}

// ---------------- GEMM (r5 version — best measured): 64x64 tile ----------------
// MODE 0: A fp32 (x), bf16-converted during LDS staging; outputs Q/K/V
//         (B,H,N,D), Q pre-scaled by log2(e).  MODE 1: A bf16; fp32 out.

template<int MODE>
__global__ __launch_bounds__(256) void gemm_kernel(
    const void* __restrict__ Ap, const short* __restrict__ Bt,
    const float* __restrict__ bias,
    short* __restrict__ outQ, short* __restrict__ outK, short* __restrict__ outV,
    float* __restrict__ outP)
{
    const int K = 256;
    int m0 = blockIdx.x * 64;
    int n0 = blockIdx.y * 64;
    int tid = threadIdx.x;
    int wave = tid >> 6, lane = tid & 63, quad = lane >> 4, lc = lane & 15;

    __shared__ __align__(16) short As[64 * 48];
    __shared__ __align__(16) short Bs[64 * 48];

    float4v acc[4];
    #pragma unroll
    for (int t = 0; t < 4; ++t) acc[t] = (float4v){0.f, 0.f, 0.f, 0.f};

    int srow = tid >> 2, sseg = tid & 3;

    for (int c = 0; c < K; c += 32) {
        __syncthreads();
        if (MODE == 0) {
            const float* src = (const float*)Ap + (size_t)(m0 + srow) * K + c + sseg * 8;
            float4 f0 = *(const float4*)src;
            float4 f1 = *(const float4*)(src + 4);
            uint4v u; u.x = cvt_pk2(f0.x, f0.y); u.y = cvt_pk2(f0.z, f0.w);
            u.z = cvt_pk2(f1.x, f1.y); u.w = cvt_pk2(f1.z, f1.w);
            *(uint4v*)(&As[srow * 48 + sseg * 8]) = u;
        } else {
            *(short8*)(&As[srow * 48 + sseg * 8]) =
                *(const short8*)((const short*)Ap + (size_t)(m0 + srow) * K + c + sseg * 8);
        }
        *(short8*)(&Bs[srow * 48 + sseg * 8]) =
            *(const short8*)(Bt + (size_t)(n0 + srow) * K + c + sseg * 8);
        __syncthreads();

        short8 af = *(short8*)(&As[(wave * 16 + lc) * 48 + quad * 8]);
        #pragma unroll
        for (int t = 0; t < 4; ++t) {
            short8 bf = *(short8*)(&Bs[(t * 16 + lc) * 48 + quad * 8]);
            acc[t] = __builtin_amdgcn_mfma_f32_16x16x32_bf16(af, bf, acc[t], 0, 0, 0);
        }
    }

    #pragma unroll
    for (int t = 0; t < 4; ++t) {
        int cg = n0 + t * 16 + lc;
        float bv = bias[cg];
        #pragma unroll
        for (int r = 0; r < 4; ++r) {
            int rg = m0 + wave * 16 + quad * 4 + r;
            float val = acc[t][r] + bv;
            if (MODE == 0) {
                int sq = cg >> 8, rem = cg & 255, h = rem >> 4, d = rem & 15;
                int b = rg >> 11, n = rg & 2047;
                if (sq == 0) val *= 1.4426950408889634f;  // fold log2(e) into Q
                short* dst = (sq == 0) ? outQ : ((sq == 1) ? outK : outV);
                dst[((((size_t)b * 16 + h) * 2048 + n) << 4) + d] = f2bf(val);
            } else {
                outP[(size_t)rg * 256 + cg] = val;
            }
        }
    }
}

// ---------------- flash attention, software-pipelined K-loop ----------------
// grid: (N/128, B*H), 256 threads (4 waves); wave w owns q rows qbase+w*32..+32.
// S^T = K*Q^T (32x32x16, C-layout col=q); exp2 in-regs; packed C regs are the
// B-operand of O^T = [V^T;1;0]*P^T (slot->key bit-swap folded into Vt staging).
// r4's divergent vf select kept verbatim: exec-masked 16-lane ds_read is the
// cheapest form (r5/r6 measured LDS-row variants slower).
// NEW (r9): loads in flight across barriers (AITER pattern) —
//  * kf prefetch distance 1: key walk is linear (c = 64*git, wraps at N), so
//    each it issues the NEXT it's two dwordx4 K loads before the exp phase.
//  * V-stage regs for super-chunk sc+256 are loaded right after the ds_write
//    of chunk sc, in flight across both barriers and 4 its of compute.

__global__ __launch_bounds__(256) void attn_kernel(
    const short* __restrict__ Q, const short* __restrict__ Kp, const short* __restrict__ V,
    short* __restrict__ Out)
{
    const int N = 2048;
    int bh = blockIdx.y;
    int b = bh >> 4, h = bh & 15;
    int tid = threadIdx.x;
    int wave = tid >> 6, lane = tid & 63;
    int m = lane & 31, hi = lane >> 5;
    int qbase = blockIdx.x * 128 + wave * 32;

    const short* Qh = Q + (size_t)bh * N * 16;
    const short* Kh = Kp + (size_t)bh * N * 16;
    const short* Vh = V + (size_t)bh * N * 16;

    __shared__ __align__(16) short Vt[16][264];

    short8 qf = *(const short8*)(Qh + (size_t)(qbase + m) * 16 + hi * 8);

    short8 ones, zeros;
    #pragma unroll
    for (int j = 0; j < 8; ++j) { ones[j] = (short)0x3F80; zeros[j] = 0; }

    float16v Oacc, zf;
    #pragma unroll
    for (int j = 0; j < 16; ++j) { Oacc[j] = 0.f; zf[j] = 0.f; }

    int sd = tid & 15, sa = tid >> 4;
    int kb = ((sa & 1) << 3) | (((sa >> 1) & 1) << 2) | ((sa >> 2) << 4);

    // ---- V staging prefetch (chunk 0) ----
    short4v vpack[4];
    #pragma unroll
    for (int cc = 0; cc < 4; ++cc) {
        const short* vp = Vh + (size_t)(cc * 64 + kb) * 16 + sd;
        vpack[cc].x = vp[0]; vpack[cc].y = vp[16];
        vpack[cc].z = vp[32]; vpack[cc].w = vp[48];
    }

    // ---- kf prefetch (it 0) ----
    short8 kf1 = *(const short8*)(Kh + (size_t)m * 16 + hi * 8);
    short8 kf2 = *(const short8*)(Kh + (size_t)(32 + m) * 16 + hi * 8);

    for (int sc = 0; sc < N; sc += 256) {
        __syncthreads();
        #pragma unroll
        for (int cc = 0; cc < 4; ++cc)
            *(short4v*)(&Vt[sd][cc * 64 + sa * 4]) = vpack[cc];
        if (sc + 256 < N) {   // V prefetch for next chunk — in flight across barrier
            #pragma unroll
            for (int cc = 0; cc < 4; ++cc) {
                const short* vp = Vh + (size_t)(sc + 256 + cc * 64 + kb) * 16 + sd;
                vpack[cc].x = vp[0]; vpack[cc].y = vp[16];
                vpack[cc].z = vp[32]; vpack[cc].w = vp[48];
            }
        }
        __syncthreads();

        #pragma unroll
        for (int it = 0; it < 4; ++it) {
            int c = sc + it * 64;
            int cn = (c + 64) & (N - 1);   // next-it key base (wraps harmlessly)

            float16v S1 = __builtin_amdgcn_mfma_f32_32x32x16_bf16(kf1, qf, zf, 0, 0, 0);
            float16v S2 = __builtin_amdgcn_mfma_f32_32x32x16_bf16(kf2, qf, zf, 0, 0, 0);

            // prefetch next it's K fragments; latency hidden by exp/pack/PV below
            kf1 = *(const short8*)(Kh + (size_t)(cn + m) * 16 + hi * 8);
            kf2 = *(const short8*)(Kh + (size_t)(cn + 32 + m) * 16 + hi * 8);

            union { uint4v u; short8 s; } pA, pB, pC, pD;
            pA.u = (uint4v){
                cvt_pk2(__builtin_amdgcn_exp2f(S1[0]), __builtin_amdgcn_exp2f(S1[1])),
                cvt_pk2(__builtin_amdgcn_exp2f(S1[2]), __builtin_amdgcn_exp2f(S1[3])),
                cvt_pk2(__builtin_amdgcn_exp2f(S1[4]), __builtin_amdgcn_exp2f(S1[5])),
                cvt_pk2(__builtin_amdgcn_exp2f(S1[6]), __builtin_amdgcn_exp2f(S1[7]))};
            pB.u = (uint4v){
                cvt_pk2(__builtin_amdgcn_exp2f(S1[8]),  __builtin_amdgcn_exp2f(S1[9])),
                cvt_pk2(__builtin_amdgcn_exp2f(S1[10]), __builtin_amdgcn_exp2f(S1[11])),
                cvt_pk2(__builtin_amdgcn_exp2f(S1[12]), __builtin_amdgcn_exp2f(S1[13])),
                cvt_pk2(__builtin_amdgcn_exp2f(S1[14]), __builtin_amdgcn_exp2f(S1[15]))};
            pC.u = (uint4v){
                cvt_pk2(__builtin_amdgcn_exp2f(S2[0]), __builtin_amdgcn_exp2f(S2[1])),
                cvt_pk2(__builtin_amdgcn_exp2f(S2[2]), __builtin_amdgcn_exp2f(S2[3])),
                cvt_pk2(__builtin_amdgcn_exp2f(S2[4]), __builtin_amdgcn_exp2f(S2[5])),
                cvt_pk2(__builtin_amdgcn_exp2f(S2[6]), __builtin_amdgcn_exp2f(S2[7]))};
            pD.u = (uint4v){
                cvt_pk2(__builtin_amdgcn_exp2f(S2[8]),  __builtin_amdgcn_exp2f(S2[9])),
                cvt_pk2(__builtin_amdgcn_exp2f(S2[10]), __builtin_amdgcn_exp2f(S2[11])),
                cvt_pk2(__builtin_amdgcn_exp2f(S2[12]), __builtin_amdgcn_exp2f(S2[13])),
                cvt_pk2(__builtin_amdgcn_exp2f(S2[14]), __builtin_amdgcn_exp2f(S2[15]))};

            #pragma unroll
            for (int p = 0; p < 4; ++p) {
                short8 vf;
                if (m < 16)      vf = *(const short8*)(&Vt[m][it * 64 + p * 16 + hi * 8]);
                else if (m == 16) vf = ones;
                else              vf = zeros;
                short8 pf = (p == 0) ? pA.s : (p == 1) ? pB.s : (p == 2) ? pC.s : pD.s;
                Oacc = __builtin_amdgcn_mfma_f32_32x32x16_bf16(vf, pf, Oacc, 0, 0, 0);
            }
        }
    }

    // epilogue: L = row 16 (reg 8, hi==0 lanes); O[q][d] = Oacc_d / L
    float Lq = __shfl(Oacc[8], m, 64);
    float inv = 1.0f / Lq;
    uint32_t o0 = cvt_pk2(Oacc[0] * inv, Oacc[1] * inv);
    uint32_t o1 = cvt_pk2(Oacc[2] * inv, Oacc[3] * inv);
    uint32_t o2 = cvt_pk2(Oacc[4] * inv, Oacc[5] * inv);
    uint32_t o3 = cvt_pk2(Oacc[6] * inv, Oacc[7] * inv);
    short* row = Out + ((size_t)(b * 2048 + qbase + m)) * 256 + h * 16;
    uint2 w0; w0.x = o0; w0.y = o1;
    uint2 w1; w1.x = o2; w1.y = o3;
    *(uint2*)(row + hi * 4) = w0;
    *(uint2*)(row + 8 + hi * 4) = w1;
}

// ---------------- launcher ----------------

extern "C" void kernel_launch(void* const* d_in, const int* in_sizes, int n_in,
                              void* d_out, int out_size, void* d_ws, size_t ws_size,
                              hipStream_t stream) {
    const float* x      = (const float*)d_in[0];
    const float* w_qkv  = (const float*)d_in[1];
    const float* b_qkv  = (const float*)d_in[2];
    const float* w_proj = (const float*)d_in[3];
    const float* b_proj = (const float*)d_in[4];
    float* out = (float*)d_out;

    short* wqkvT  = (short*)d_ws;          // 768*256
    short* wprojT = wqkvT + 196608;        // 256*256
    short* Qb     = wprojT + 65536;        // 4*16*2048*16
    short* Kb     = Qb + 2097152;
    short* Vb     = Kb + 2097152;
    short* Ab     = Vb + 2097152;          // 8192*256 attention output

    cvtW_kernel<<<1024, 256, 0, stream>>>(w_qkv, w_proj, wqkvT, wprojT);

    gemm_kernel<0><<<dim3(128, 12), 256, 0, stream>>>(x, wqkvT, b_qkv, Qb, Kb, Vb, nullptr);

    attn_kernel<<<dim3(16, 64), 256, 0, stream>>>(Qb, Kb, Vb, Ab);

    gemm_kernel<1><<<dim3(128, 4), 256, 0, stream>>>(Ab, wprojT, b_proj,
                                                     nullptr, nullptr, nullptr, out);
}